// Round 2
// baseline (651.102 us; speedup 1.0000x reference)
//
#include <hip/hip_runtime.h>

// Log-sparse attention, B=4 H=8 L=4096 E=64 fp32, win_len<=32.
// Lane-per-query layout: each thread owns one query row; Q and the output
// accumulator live in registers; dot products are in-lane FMAs (NO cross-lane
// shuffles -- round 1 was ds_bpermute-throughput-bound).
// Window keys (dist 0..32, 33x reuse) staged in LDS as bf16.
// Pow2 keys (dist 64..2048, used by exactly 1 lane) read direct from global fp32.

constexpr int L       = 4096;      // sequence length (fixed by problem)
constexpr int E       = 64;        // head dim
constexpr int QB      = 256;       // queries per block (= blockDim.x)
constexpr int WMAX    = 32;        // max supported win_len
constexpr int WROWS   = QB + WMAX; // 288 staged rows
constexpr int RSTRIDE = 144;       // LDS row stride bytes (128 data + 16 pad -> conflict-free b128)
constexpr int TPB_SEQ = L / QB;    // tiles per (b,h) sequence = 16
constexpr int NP2     = 6;         // pow2 distances 64,128,...,2048

__device__ __forceinline__ unsigned pack2_bf16(float a, float b) {
    unsigned ua = __float_as_uint(a);
    unsigned ub = __float_as_uint(b);
    unsigned ra = (ua + 0x7FFFu + ((ua >> 16) & 1u)) >> 16;  // RNE
    unsigned rb = (ub + 0x7FFFu + ((ub >> 16) & 1u)) >> 16;
    return ra | (rb << 16);
}
__device__ __forceinline__ float bf_lo(unsigned w) { return __uint_as_float(w << 16); }
__device__ __forceinline__ float bf_hi(unsigned w) { return __uint_as_float(w & 0xFFFF0000u); }

__global__ __launch_bounds__(256, 2) void logsparse_attn(
    const float* __restrict__ q,
    const float* __restrict__ k,
    const float* __restrict__ v,
    float* __restrict__ out,
    const int* __restrict__ win_ptr)
{
    __shared__ alignas(16) unsigned char buf[WROWS * RSTRIDE];  // 41472 B

    const int bid = blockIdx.x, nb = gridDim.x;
    int swz = bid;
    if ((nb & 7) == 0) {                       // bijective XCD swizzle
        const int cpx = nb >> 3;
        swz = (bid & 7) * cpx + (bid >> 3);
    }
    const int bh  = swz / TPB_SEQ;
    const int t   = (swz % TPB_SEQ) * QB;
    const int tid = threadIdx.x;
    const int i   = t + tid;                   // this thread's query position
    int win = *win_ptr; win = min(win, WMAX);

    const size_t base = (size_t)bh * (L * E);
    const float* kb = k + base;
    const float* vb = v + base;

    // ---- stage K window rows [t-WMAX, t+QB) as bf16 (coalesced) ----
    #pragma unroll
    for (int it = 0; it < (WROWS * (E / 4)) / QB; ++it) {   // 18 iters
        int idx = tid + it * QB;
        int row = idx >> 4, e4 = idx & 15;
        int j = t - WMAX + row; j = max(j, 0);
        const float4 f = *(const float4*)(kb + (size_t)j * E + e4 * 4);
        uint2 pk; pk.x = pack2_bf16(f.x, f.y); pk.y = pack2_bf16(f.z, f.w);
        *(uint2*)(buf + row * RSTRIDE + e4 * 8) = pk;
    }

    // ---- this query's q row into registers, scale folded (1/sqrt(64)) ----
    float qr[E];
    #pragma unroll
    for (int e4 = 0; e4 < 16; ++e4) {
        float4 f = *(const float4*)(q + base + (size_t)i * E + e4 * 4);
        qr[e4*4+0] = f.x * 0.125f; qr[e4*4+1] = f.y * 0.125f;
        qr[e4*4+2] = f.z * 0.125f; qr[e4*4+3] = f.w * 0.125f;
    }

    __syncthreads();

    // ---- window scores, dist o = 0..WMAX (in-lane dots from LDS) ----
    float s[WMAX + 1];
    #pragma unroll
    for (int o = 0; o <= WMAX; ++o) {
        const int4* rp = (const int4*)(buf + (tid + (WMAX - o)) * RSTRIDE);
        float a0 = 0.f, a1 = 0.f, a2 = 0.f, a3 = 0.f;
        #pragma unroll
        for (int e8 = 0; e8 < 8; ++e8) {
            int4 w = rp[e8]; int eb = e8 * 8;
            a0 = fmaf(bf_lo(w.x), qr[eb+0], a0); a1 = fmaf(bf_hi(w.x), qr[eb+1], a1);
            a2 = fmaf(bf_lo(w.y), qr[eb+2], a2); a3 = fmaf(bf_hi(w.y), qr[eb+3], a3);
            a0 = fmaf(bf_lo(w.z), qr[eb+4], a0); a1 = fmaf(bf_hi(w.z), qr[eb+5], a1);
            a2 = fmaf(bf_lo(w.w), qr[eb+6], a2); a3 = fmaf(bf_hi(w.w), qr[eb+7], a3);
        }
        const bool isp2  = (o > 0) && ((o & (o - 1)) == 0);
        const bool valid = ((o <= win) || isp2) && (o <= i);
        s[o] = valid ? ((a0 + a1) + (a2 + a3)) : -3.0e38f;
    }

    // ---- pow2 scores, dist d = 64..2048 (direct global, 1 row per lane) ----
    float sp[NP2];
    #pragma unroll
    for (int dd = 0; dd < NP2; ++dd) {
        const int d = 64 << dd;
        sp[dd] = -3.0e38f;
        if ((i | 63) >= d) {                       // wave-uniform skip
            const bool vld = (i >= d);
            const int j = vld ? (i - d) : 0;
            const float* kr = kb + (size_t)j * E;
            float a0 = 0.f, a1 = 0.f, a2 = 0.f, a3 = 0.f;
            #pragma unroll
            for (int e4 = 0; e4 < 16; ++e4) {
                float4 f = *(const float4*)(kr + e4 * 4);
                a0 = fmaf(f.x, qr[e4*4+0], a0); a1 = fmaf(f.y, qr[e4*4+1], a1);
                a2 = fmaf(f.z, qr[e4*4+2], a2); a3 = fmaf(f.w, qr[e4*4+3], a3);
            }
            if (vld) sp[dd] = (a0 + a1) + (a2 + a3);
        }
    }

    // ---- in-lane softmax ----
    float m = s[0];
    #pragma unroll
    for (int o = 1; o <= WMAX; ++o) m = fmaxf(m, s[o]);
    #pragma unroll
    for (int dd = 0; dd < NP2; ++dd) m = fmaxf(m, sp[dd]);

    float den = 0.f, p[WMAX + 1], pp[NP2];
    #pragma unroll
    for (int o = 0; o <= WMAX; ++o) { p[o] = __expf(s[o] - m); den += p[o]; }
    #pragma unroll
    for (int dd = 0; dd < NP2; ++dd) { pp[dd] = __expf(sp[dd] - m); den += pp[dd]; }

    __syncthreads();   // everyone done reading K from buf

    // ---- restage V window rows as bf16 ----
    #pragma unroll
    for (int it = 0; it < (WROWS * (E / 4)) / QB; ++it) {
        int idx = tid + it * QB;
        int row = idx >> 4, e4 = idx & 15;
        int j = t - WMAX + row; j = max(j, 0);
        const float4 f = *(const float4*)(vb + (size_t)j * E + e4 * 4);
        uint2 pk; pk.x = pack2_bf16(f.x, f.y); pk.y = pack2_bf16(f.z, f.w);
        *(uint2*)(buf + row * RSTRIDE + e4 * 8) = pk;
    }

    __syncthreads();

    // ---- PV accumulate ----
    float acc[E];
    #pragma unroll
    for (int e = 0; e < E; ++e) acc[e] = 0.f;

    #pragma unroll
    for (int o = 0; o <= WMAX; ++o) {
        const int4* rp = (const int4*)(buf + (tid + (WMAX - o)) * RSTRIDE);
        const float po = p[o];
        #pragma unroll
        for (int e8 = 0; e8 < 8; ++e8) {
            int4 w = rp[e8]; int eb = e8 * 8;
            acc[eb+0] = fmaf(bf_lo(w.x), po, acc[eb+0]);
            acc[eb+1] = fmaf(bf_hi(w.x), po, acc[eb+1]);
            acc[eb+2] = fmaf(bf_lo(w.y), po, acc[eb+2]);
            acc[eb+3] = fmaf(bf_hi(w.y), po, acc[eb+3]);
            acc[eb+4] = fmaf(bf_lo(w.z), po, acc[eb+4]);
            acc[eb+5] = fmaf(bf_hi(w.z), po, acc[eb+5]);
            acc[eb+6] = fmaf(bf_lo(w.w), po, acc[eb+6]);
            acc[eb+7] = fmaf(bf_hi(w.w), po, acc[eb+7]);
        }
    }

    #pragma unroll
    for (int dd = 0; dd < NP2; ++dd) {
        const int d = 64 << dd;
        if ((i | 63) >= d) {
            const int j = max(i - d, 0);
            const float* vr = vb + (size_t)j * E;
            const float pd = pp[dd];
            #pragma unroll
            for (int e4 = 0; e4 < 16; ++e4) {
                float4 f = *(const float4*)(vr + e4 * 4);
                acc[e4*4+0] = fmaf(f.x, pd, acc[e4*4+0]);
                acc[e4*4+1] = fmaf(f.y, pd, acc[e4*4+1]);
                acc[e4*4+2] = fmaf(f.z, pd, acc[e4*4+2]);
                acc[e4*4+3] = fmaf(f.w, pd, acc[e4*4+3]);
            }
        }
    }

    // ---- write out (scattered float4; L2 write-combines full rows) ----
    const float inv = 1.0f / den;
    #pragma unroll
    for (int e4 = 0; e4 < 16; ++e4) {
        float4 o4;
        o4.x = acc[e4*4+0] * inv; o4.y = acc[e4*4+1] * inv;
        o4.z = acc[e4*4+2] * inv; o4.w = acc[e4*4+3] * inv;
        *(float4*)(out + base + (size_t)i * E + e4 * 4) = o4;
    }
}

extern "C" void kernel_launch(void* const* d_in, const int* in_sizes, int n_in,
                              void* d_out, int out_size, void* d_ws, size_t ws_size,
                              hipStream_t stream) {
    const float* q = (const float*)d_in[0];
    const float* k = (const float*)d_in[1];
    const float* v = (const float*)d_in[2];
    const int* win = (const int*)d_in[3];
    float* out = (float*)d_out;

    const int n_rows = in_sizes[0] / E;       // B*H*L = 131072
    const int blocks = n_rows / QB;           // 512
    logsparse_attn<<<blocks, QB, 0, stream>>>(q, k, v, out, win);
}

// Round 3
// 228.046 us; speedup vs baseline: 2.8551x; 2.8551x over previous
//
#include <hip/hip_runtime.h>

// Log-sparse attention, B=4 H=8 L=4096 E=64 fp32, win_len<=32.
// Lane-per-query: each thread owns one query row. Round-3 change: E-split
// two-pass scores and PV so peak live floats ~90 (round 2 spilled 1 GB of
// scratch with qr[64]+acc[64] under a 128-VGPR cap). No cross-lane shuffles.
// Window keys (dist 0..32) staged in LDS as bf16; pow2 keys (64..2048) read
// direct from global fp32 (one row per lane, dense 16KB wave footprint).

constexpr int L       = 4096;
constexpr int E       = 64;
constexpr int QB      = 256;        // queries per block
constexpr int WMAX    = 32;
constexpr int WROWS   = QB + WMAX;  // 288 staged rows
constexpr int RSTRIDE = 144;        // bytes: 128 data + 16 pad (0 conflicts measured)
constexpr int TPB_SEQ = L / QB;     // 16
constexpr int NP2     = 6;          // dists 64,128,...,2048
constexpr int NK      = WMAX + 1 + NP2;  // 39 candidate keys

__device__ __forceinline__ unsigned pack2_bf16(float a, float b) {
    unsigned ua = __float_as_uint(a);
    unsigned ub = __float_as_uint(b);
    unsigned ra = (ua + 0x7FFFu + ((ua >> 16) & 1u)) >> 16;  // RNE
    unsigned rb = (ub + 0x7FFFu + ((ub >> 16) & 1u)) >> 16;
    return ra | (rb << 16);
}
__device__ __forceinline__ float bf_lo(unsigned w) { return __uint_as_float(w << 16); }
__device__ __forceinline__ float bf_hi(unsigned w) { return __uint_as_float(w & 0xFFFF0000u); }

__global__ __launch_bounds__(256) void logsparse_attn(
    const float* __restrict__ q,
    const float* __restrict__ k,
    const float* __restrict__ v,
    float* __restrict__ out,
    const int* __restrict__ win_ptr)
{
    __shared__ alignas(16) unsigned char buf[WROWS * RSTRIDE];  // 41472 B

    const int bid = blockIdx.x, nb = gridDim.x;
    int swz = bid;
    if ((nb & 7) == 0) {                       // bijective XCD swizzle
        const int cpx = nb >> 3;
        swz = (bid & 7) * cpx + (bid >> 3);
    }
    const int bh  = swz / TPB_SEQ;
    const int t   = (swz % TPB_SEQ) * QB;
    const int tid = threadIdx.x;
    const int i   = t + tid;
    int win = *win_ptr; win = min(win, WMAX);

    const size_t base = (size_t)bh * (L * E);
    const float* kb = k + base;
    const float* vb = v + base;

    // ---- stage K window rows [t-WMAX, t+QB) as bf16 (coalesced) ----
    #pragma unroll
    for (int it = 0; it < (WROWS * (E / 4)) / QB; ++it) {   // 18 iters
        int idx = tid + it * QB;
        int row = idx >> 4, e4 = idx & 15;
        int j = t - WMAX + row; j = max(j, 0);
        const float4 f = *(const float4*)(kb + (size_t)j * E + e4 * 4);
        uint2 pk; pk.x = pack2_bf16(f.x, f.y); pk.y = pack2_bf16(f.z, f.w);
        *(uint2*)(buf + row * RSTRIDE + e4 * 8) = pk;
    }
    __syncthreads();

    // ---- scores: two passes over E halves, sc[] accumulates ----
    float sc[NK];
    #pragma unroll
    for (int a = 0; a < NK; ++a) sc[a] = 0.f;

    #pragma unroll 1
    for (int h = 0; h < 2; ++h) {
        // this half of q, scale folded (1/sqrt(64) = 0.125)
        float qh[32];
        const float* qp = q + base + (size_t)i * E + h * 32;
        #pragma unroll
        for (int e4 = 0; e4 < 8; ++e4) {
            float4 f = *(const float4*)(qp + e4 * 4);
            qh[e4*4+0] = f.x * 0.125f; qh[e4*4+1] = f.y * 0.125f;
            qh[e4*4+2] = f.z * 0.125f; qh[e4*4+3] = f.w * 0.125f;
        }
        // window offsets 0..32 from LDS
        #pragma unroll
        for (int o = 0; o <= WMAX; ++o) {
            const int4* rp = (const int4*)(buf + (tid + (WMAX - o)) * RSTRIDE + h * 64);
            float a0 = 0.f, a1 = 0.f, a2 = 0.f, a3 = 0.f;
            #pragma unroll
            for (int e8 = 0; e8 < 4; ++e8) {
                int4 w = rp[e8]; int eb = e8 * 8;
                a0 = fmaf(bf_lo(w.x), qh[eb+0], a0); a1 = fmaf(bf_hi(w.x), qh[eb+1], a1);
                a2 = fmaf(bf_lo(w.y), qh[eb+2], a2); a3 = fmaf(bf_hi(w.y), qh[eb+3], a3);
                a0 = fmaf(bf_lo(w.z), qh[eb+4], a0); a1 = fmaf(bf_hi(w.z), qh[eb+5], a1);
                a2 = fmaf(bf_lo(w.w), qh[eb+6], a2); a3 = fmaf(bf_hi(w.w), qh[eb+7], a3);
            }
            sc[o] += (a0 + a1) + (a2 + a3);
        }
        // pow2 dists from global
        #pragma unroll
        for (int dd = 0; dd < NP2; ++dd) {
            const int d = 64 << dd;
            if ((i | 63) >= d) {                 // wave-uniform skip
                const int j = max(i - d, 0);
                const float* kr = kb + (size_t)j * E + h * 32;
                float a0 = 0.f, a1 = 0.f, a2 = 0.f, a3 = 0.f;
                #pragma unroll
                for (int e4 = 0; e4 < 8; ++e4) {
                    float4 f = *(const float4*)(kr + e4 * 4);
                    a0 = fmaf(f.x, qh[e4*4+0], a0); a1 = fmaf(f.y, qh[e4*4+1], a1);
                    a2 = fmaf(f.z, qh[e4*4+2], a2); a3 = fmaf(f.w, qh[e4*4+3], a3);
                }
                sc[WMAX + 1 + dd] += (a0 + a1) + (a2 + a3);
            }
        }
    }

    // ---- masks ----
    #pragma unroll
    for (int o = 0; o <= WMAX; ++o) {
        const bool isp2  = (o > 0) && ((o & (o - 1)) == 0);
        const bool valid = ((o <= win) || isp2) && (o <= i);
        if (!valid) sc[o] = -3.0e38f;
    }
    #pragma unroll
    for (int dd = 0; dd < NP2; ++dd)
        if (i < (64 << dd)) sc[WMAX + 1 + dd] = -3.0e38f;

    // ---- in-lane softmax over 39 candidates ----
    float m = sc[0];
    #pragma unroll
    for (int a = 1; a < NK; ++a) m = fmaxf(m, sc[a]);
    float den = 0.f;
    #pragma unroll
    for (int a = 0; a < NK; ++a) { sc[a] = __expf(sc[a] - m); den += sc[a]; }
    const float inv = 1.0f / den;

    __syncthreads();   // done reading K from buf

    // ---- restage V window rows as bf16 ----
    #pragma unroll
    for (int it = 0; it < (WROWS * (E / 4)) / QB; ++it) {
        int idx = tid + it * QB;
        int row = idx >> 4, e4 = idx & 15;
        int j = t - WMAX + row; j = max(j, 0);
        const float4 f = *(const float4*)(vb + (size_t)j * E + e4 * 4);
        uint2 pk; pk.x = pack2_bf16(f.x, f.y); pk.y = pack2_bf16(f.z, f.w);
        *(uint2*)(buf + row * RSTRIDE + e4 * 8) = pk;
    }
    __syncthreads();

    // ---- PV: two passes over E halves, write each half out ----
    #pragma unroll 1
    for (int h = 0; h < 2; ++h) {
        float acc[32];
        #pragma unroll
        for (int e = 0; e < 32; ++e) acc[e] = 0.f;

        #pragma unroll
        for (int o = 0; o <= WMAX; ++o) {
            const int4* rp = (const int4*)(buf + (tid + (WMAX - o)) * RSTRIDE + h * 64);
            const float po = sc[o];
            #pragma unroll
            for (int e8 = 0; e8 < 4; ++e8) {
                int4 w = rp[e8]; int eb = e8 * 8;
                acc[eb+0] = fmaf(bf_lo(w.x), po, acc[eb+0]);
                acc[eb+1] = fmaf(bf_hi(w.x), po, acc[eb+1]);
                acc[eb+2] = fmaf(bf_lo(w.y), po, acc[eb+2]);
                acc[eb+3] = fmaf(bf_hi(w.y), po, acc[eb+3]);
                acc[eb+4] = fmaf(bf_lo(w.z), po, acc[eb+4]);
                acc[eb+5] = fmaf(bf_hi(w.z), po, acc[eb+5]);
                acc[eb+6] = fmaf(bf_lo(w.w), po, acc[eb+6]);
                acc[eb+7] = fmaf(bf_hi(w.w), po, acc[eb+7]);
            }
        }
        #pragma unroll
        for (int dd = 0; dd < NP2; ++dd) {
            const int d = 64 << dd;
            if ((i | 63) >= d) {
                const int j = max(i - d, 0);
                const float* vr = vb + (size_t)j * E + h * 32;
                const float pd = sc[WMAX + 1 + dd];   // exp()==0 if masked
                #pragma unroll
                for (int e4 = 0; e4 < 8; ++e4) {
                    float4 f = *(const float4*)(vr + e4 * 4);
                    acc[e4*4+0] = fmaf(f.x, pd, acc[e4*4+0]);
                    acc[e4*4+1] = fmaf(f.y, pd, acc[e4*4+1]);
                    acc[e4*4+2] = fmaf(f.z, pd, acc[e4*4+2]);
                    acc[e4*4+3] = fmaf(f.w, pd, acc[e4*4+3]);
                }
            }
        }

        float* op = out + base + (size_t)i * E + h * 32;
        #pragma unroll
        for (int e4 = 0; e4 < 8; ++e4) {
            float4 o4;
            o4.x = acc[e4*4+0] * inv; o4.y = acc[e4*4+1] * inv;
            o4.z = acc[e4*4+2] * inv; o4.w = acc[e4*4+3] * inv;
            *(float4*)(op + e4 * 4) = o4;
        }
    }
}

extern "C" void kernel_launch(void* const* d_in, const int* in_sizes, int n_in,
                              void* d_out, int out_size, void* d_ws, size_t ws_size,
                              hipStream_t stream) {
    const float* q = (const float*)d_in[0];
    const float* k = (const float*)d_in[1];
    const float* v = (const float*)d_in[2];
    const int* win = (const int*)d_in[3];
    float* out = (float*)d_out;

    const int n_rows = in_sizes[0] / E;       // B*H*L = 131072
    const int blocks = n_rows / QB;           // 512
    logsparse_attn<<<blocks, QB, 0, stream>>>(q, k, v, out, win);
}

// Round 4
// 175.266 us; speedup vs baseline: 3.7149x; 1.3011x over previous
//
#include <hip/hip_runtime.h>

// Log-sparse attention, B=4 H=8 L=4096 E=64 fp32, win_len<=32.
// Lane-per-query. Round-4: fight register-allocator spill by PHASE ORDER:
//  - scores: pow2 global-load phase first (small live set under the hoisted
//    load spike), window LDS phase second;
//  - PV: window phase first, pow2 load phase last (scw[] dead by then).
// q kept packed bf16 in registers (16 regs/half). K/V window staged LDS bf16.

constexpr int L       = 4096;
constexpr int E       = 64;
constexpr int QB      = 256;
constexpr int WMAX    = 32;
constexpr int WROWS   = QB + WMAX;   // 288
constexpr int RSTRIDE = 144;         // 128 B data + 16 pad
constexpr int TPB_SEQ = L / QB;      // 16
constexpr int NP2     = 6;           // dists 64..2048

__device__ __forceinline__ unsigned pack2_bf16(float a, float b) {
    unsigned ua = __float_as_uint(a);
    unsigned ub = __float_as_uint(b);
    unsigned ra = (ua + 0x7FFFu + ((ua >> 16) & 1u)) >> 16;  // RNE
    unsigned rb = (ub + 0x7FFFu + ((ub >> 16) & 1u)) >> 16;
    return ra | (rb << 16);
}
__device__ __forceinline__ float bf_lo(unsigned w) { return __uint_as_float(w << 16); }
__device__ __forceinline__ float bf_hi(unsigned w) { return __uint_as_float(w & 0xFFFF0000u); }

__global__ __launch_bounds__(256) void logsparse_attn(
    const float* __restrict__ q,
    const float* __restrict__ k,
    const float* __restrict__ v,
    float* __restrict__ out,
    const int* __restrict__ win_ptr)
{
    __shared__ alignas(16) unsigned char buf[WROWS * RSTRIDE];  // 41472 B

    const int bid = blockIdx.x, nb = gridDim.x;
    int swz = bid;
    if ((nb & 7) == 0) {                        // bijective XCD swizzle
        const int cpx = nb >> 3;
        swz = (bid & 7) * cpx + (bid >> 3);
    }
    const int bh  = swz / TPB_SEQ;
    const int t   = (swz % TPB_SEQ) * QB;
    const int tid = threadIdx.x;
    const int i   = t + tid;
    int win = *win_ptr; win = min(win, WMAX);

    const size_t base = (size_t)bh * (L * E);
    const float* kb = k + base;
    const float* vb = v + base;

    // ---- stage K window rows [t-WMAX, t+QB) as bf16 (coalesced) ----
    #pragma unroll
    for (int it = 0; it < (WROWS * (E / 4)) / QB; ++it) {   // 18 iters
        int idx = tid + it * QB;
        int row = idx >> 4, e4 = idx & 15;
        int j = t - WMAX + row; j = max(j, 0);
        const float4 f = *(const float4*)(kb + (size_t)j * E + e4 * 4);
        uint2 pk; pk.x = pack2_bf16(f.x, f.y); pk.y = pack2_bf16(f.z, f.w);
        *(uint2*)(buf + row * RSTRIDE + e4 * 8) = pk;
    }
    __syncthreads();

    float scw[WMAX + 1];
    float scp[NP2];
    #pragma unroll
    for (int o = 0; o <= WMAX; ++o) scw[o] = 0.f;
    #pragma unroll
    for (int dd = 0; dd < NP2; ++dd) scp[dd] = 0.f;

    // ---- scores: two E-halves; within each, pow2(global) THEN window(LDS) ----
    #pragma unroll 1
    for (int h = 0; h < 2; ++h) {
        // q half, scaled (1/8) and packed bf16 -> 16 regs
        unsigned qp[16];
        const float* qptr = q + base + (size_t)i * E + h * 32;
        #pragma unroll
        for (int e4 = 0; e4 < 8; ++e4) {
            float4 f = *(const float4*)(qptr + e4 * 4);
            qp[e4*2+0] = pack2_bf16(f.x * 0.125f, f.y * 0.125f);
            qp[e4*2+1] = pack2_bf16(f.z * 0.125f, f.w * 0.125f);
        }

        // pow2 dists 64..2048: per-lane row from global (fp32)
        #pragma unroll
        for (int dd = 0; dd < NP2; ++dd) {
            const int d = 64 << dd;
            if ((i | 63) >= d) {                // wave-uniform skip
                const int j = max(i - d, 0);
                const float* kr = kb + (size_t)j * E + h * 32;
                float a0 = 0.f, a1 = 0.f, a2 = 0.f, a3 = 0.f;
                #pragma unroll
                for (int e4 = 0; e4 < 8; ++e4) {
                    float4 f = *(const float4*)(kr + e4 * 4);
                    unsigned w0 = qp[e4*2+0], w1 = qp[e4*2+1];
                    a0 = fmaf(f.x, bf_lo(w0), a0); a1 = fmaf(f.y, bf_hi(w0), a1);
                    a2 = fmaf(f.z, bf_lo(w1), a2); a3 = fmaf(f.w, bf_hi(w1), a3);
                }
                scp[dd] += (a0 + a1) + (a2 + a3);
            }
        }

        __builtin_amdgcn_sched_barrier(0);      // keep load spike out of window phase

        // window offsets 0..32 from LDS (bf16)
        #pragma unroll
        for (int o = 0; o <= WMAX; ++o) {
            const int4* rp = (const int4*)(buf + (tid + (WMAX - o)) * RSTRIDE + h * 64);
            float a0 = 0.f, a1 = 0.f, a2 = 0.f, a3 = 0.f;
            #pragma unroll
            for (int e8 = 0; e8 < 4; ++e8) {
                int4 w = rp[e8];
                unsigned q0 = qp[e8*4+0], q1 = qp[e8*4+1], q2 = qp[e8*4+2], q3 = qp[e8*4+3];
                a0 = fmaf(bf_lo(w.x), bf_lo(q0), a0); a1 = fmaf(bf_hi(w.x), bf_hi(q0), a1);
                a2 = fmaf(bf_lo(w.y), bf_lo(q1), a2); a3 = fmaf(bf_hi(w.y), bf_hi(q1), a3);
                a0 = fmaf(bf_lo(w.z), bf_lo(q2), a0); a1 = fmaf(bf_hi(w.z), bf_hi(q2), a1);
                a2 = fmaf(bf_lo(w.w), bf_lo(q3), a2); a3 = fmaf(bf_hi(w.w), bf_hi(q3), a3);
            }
            scw[o] += (a0 + a1) + (a2 + a3);
        }
        __builtin_amdgcn_sched_barrier(0);
    }

    // ---- masks ----
    #pragma unroll
    for (int o = 0; o <= WMAX; ++o) {
        const bool isp2  = (o > 0) && ((o & (o - 1)) == 0);
        const bool valid = ((o <= win) || isp2) && (o <= i);
        if (!valid) scw[o] = -3.0e38f;
    }
    #pragma unroll
    for (int dd = 0; dd < NP2; ++dd)
        if (i < (64 << dd)) scp[dd] = -3.0e38f;

    // ---- in-lane softmax over 39 candidates ----
    float m = scw[0];
    #pragma unroll
    for (int o = 1; o <= WMAX; ++o) m = fmaxf(m, scw[o]);
    #pragma unroll
    for (int dd = 0; dd < NP2; ++dd) m = fmaxf(m, scp[dd]);
    float den = 0.f;
    #pragma unroll
    for (int o = 0; o <= WMAX; ++o) { scw[o] = __expf(scw[o] - m); den += scw[o]; }
    #pragma unroll
    for (int dd = 0; dd < NP2; ++dd) { scp[dd] = __expf(scp[dd] - m); den += scp[dd]; }
    const float inv = 1.0f / den;

    __syncthreads();   // done reading K from buf

    // ---- restage V window rows as bf16 ----
    #pragma unroll
    for (int it = 0; it < (WROWS * (E / 4)) / QB; ++it) {
        int idx = tid + it * QB;
        int row = idx >> 4, e4 = idx & 15;
        int j = t - WMAX + row; j = max(j, 0);
        const float4 f = *(const float4*)(vb + (size_t)j * E + e4 * 4);
        uint2 pk; pk.x = pack2_bf16(f.x, f.y); pk.y = pack2_bf16(f.z, f.w);
        *(uint2*)(buf + row * RSTRIDE + e4 * 8) = pk;
    }
    __syncthreads();

    // ---- PV: two E-halves; window(LDS) first, pow2(global) LAST ----
    #pragma unroll 1
    for (int h = 0; h < 2; ++h) {
        float acc[32];
        #pragma unroll
        for (int e = 0; e < 32; ++e) acc[e] = 0.f;

        #pragma unroll
        for (int o = 0; o <= WMAX; ++o) {
            const int4* rp = (const int4*)(buf + (tid + (WMAX - o)) * RSTRIDE + h * 64);
            const float po = scw[o];
            #pragma unroll
            for (int e8 = 0; e8 < 4; ++e8) {
                int4 w = rp[e8]; int eb = e8 * 8;
                acc[eb+0] = fmaf(bf_lo(w.x), po, acc[eb+0]);
                acc[eb+1] = fmaf(bf_hi(w.x), po, acc[eb+1]);
                acc[eb+2] = fmaf(bf_lo(w.y), po, acc[eb+2]);
                acc[eb+3] = fmaf(bf_hi(w.y), po, acc[eb+3]);
                acc[eb+4] = fmaf(bf_lo(w.z), po, acc[eb+4]);
                acc[eb+5] = fmaf(bf_hi(w.z), po, acc[eb+5]);
                acc[eb+6] = fmaf(bf_lo(w.w), po, acc[eb+6]);
                acc[eb+7] = fmaf(bf_hi(w.w), po, acc[eb+7]);
            }
        }

        __builtin_amdgcn_sched_barrier(0);      // scw now dead; pow2 load spike alone

        #pragma unroll
        for (int dd = 0; dd < NP2; ++dd) {
            const int d = 64 << dd;
            if ((i | 63) >= d) {
                const int j = max(i - d, 0);
                const float* vr = vb + (size_t)j * E + h * 32;
                const float pd = scp[dd];          // exp()==0 if masked
                #pragma unroll
                for (int e4 = 0; e4 < 8; ++e4) {
                    float4 f = *(const float4*)(vr + e4 * 4);
                    acc[e4*4+0] = fmaf(f.x, pd, acc[e4*4+0]);
                    acc[e4*4+1] = fmaf(f.y, pd, acc[e4*4+1]);
                    acc[e4*4+2] = fmaf(f.z, pd, acc[e4*4+2]);
                    acc[e4*4+3] = fmaf(f.w, pd, acc[e4*4+3]);
                }
            }
        }

        float* op = out + base + (size_t)i * E + h * 32;
        #pragma unroll
        for (int e4 = 0; e4 < 8; ++e4) {
            float4 o4;
            o4.x = acc[e4*4+0] * inv; o4.y = acc[e4*4+1] * inv;
            o4.z = acc[e4*4+2] * inv; o4.w = acc[e4*4+3] * inv;
            *(float4*)(op + e4 * 4) = o4;
        }
        __builtin_amdgcn_sched_barrier(0);
    }
}

extern "C" void kernel_launch(void* const* d_in, const int* in_sizes, int n_in,
                              void* d_out, int out_size, void* d_ws, size_t ws_size,
                              hipStream_t stream) {
    const float* q = (const float*)d_in[0];
    const float* k = (const float*)d_in[1];
    const float* v = (const float*)d_in[2];
    const int* win = (const int*)d_in[3];
    float* out = (float*)d_out;

    const int n_rows = in_sizes[0] / E;       // B*H*L = 131072
    const int blocks = n_rows / QB;           // 512
    logsparse_attn<<<blocks, QB, 0, stream>>>(q, k, v, out, win);
}

// Round 5
// 100.472 us; speedup vs baseline: 6.4804x; 1.7444x over previous
//
#include <hip/hip_runtime.h>

// Log-sparse attention, B=4 H=8 L=4096 E=64 fp32, win_len<=32.
// Lane-per-query. Round-5: kill the residual spill by BOUNDING IN-FLIGHT
// LOADS (partial unroll: pow2 loops unroll 1, window loops unroll 4) so the
// scheduler can't cluster 192 load-dest regs, and force 128-VGPR budget via
// __launch_bounds__(256,2) -> 2 blocks/CU. Peak live set ~95 floats.

constexpr int L       = 4096;
constexpr int E       = 64;
constexpr int QB      = 256;
constexpr int WMAX    = 32;
constexpr int WROWS   = QB + WMAX;   // 288
constexpr int RSTRIDE = 144;         // 128 B data + 16 pad
constexpr int TPB_SEQ = L / QB;      // 16
constexpr int NP2     = 6;           // dists 64..2048

__device__ __forceinline__ unsigned pack2_bf16(float a, float b) {
    unsigned ua = __float_as_uint(a);
    unsigned ub = __float_as_uint(b);
    unsigned ra = (ua + 0x7FFFu + ((ua >> 16) & 1u)) >> 16;  // RNE
    unsigned rb = (ub + 0x7FFFu + ((ub >> 16) & 1u)) >> 16;
    return ra | (rb << 16);
}
__device__ __forceinline__ float bf_lo(unsigned w) { return __uint_as_float(w << 16); }
__device__ __forceinline__ float bf_hi(unsigned w) { return __uint_as_float(w & 0xFFFF0000u); }

__global__ __launch_bounds__(256, 2) void logsparse_attn(
    const float* __restrict__ q,
    const float* __restrict__ k,
    const float* __restrict__ v,
    float* __restrict__ out,
    const int* __restrict__ win_ptr)
{
    __shared__ alignas(16) unsigned char buf[WROWS * RSTRIDE];  // 41472 B

    const int bid = blockIdx.x, nb = gridDim.x;
    int swz = bid;
    if ((nb & 7) == 0) {                        // bijective XCD swizzle
        const int cpx = nb >> 3;
        swz = (bid & 7) * cpx + (bid >> 3);
    }
    const int bh  = swz / TPB_SEQ;
    const int t   = (swz % TPB_SEQ) * QB;
    const int tid = threadIdx.x;
    const int i   = t + tid;
    int win = *win_ptr; win = min(win, WMAX);

    const size_t base = (size_t)bh * (L * E);
    const float* kb = k + base;
    const float* vb = v + base;

    // ---- stage K window rows [t-WMAX, t+QB) as bf16 (coalesced) ----
    #pragma unroll 6
    for (int it = 0; it < (WROWS * (E / 4)) / QB; ++it) {   // 18 iters
        int idx = tid + it * QB;
        int row = idx >> 4, e4 = idx & 15;
        int j = t - WMAX + row; j = max(j, 0);
        const float4 f = *(const float4*)(kb + (size_t)j * E + e4 * 4);
        uint2 pk; pk.x = pack2_bf16(f.x, f.y); pk.y = pack2_bf16(f.z, f.w);
        *(uint2*)(buf + row * RSTRIDE + e4 * 8) = pk;
    }
    __syncthreads();

    float scw[WMAX + 1];
    float scp[NP2];
    #pragma unroll
    for (int o = 0; o <= WMAX; ++o) scw[o] = 0.f;
    #pragma unroll
    for (int dd = 0; dd < NP2; ++dd) scp[dd] = 0.f;

    // ---- scores: two E-halves; within each, pow2(global) THEN window(LDS) ----
    #pragma unroll 1
    for (int h = 0; h < 2; ++h) {
        // q half, scaled (1/8) and packed bf16 -> 16 regs
        unsigned qp[16];
        const float* qptr = q + base + (size_t)i * E + h * 32;
        #pragma unroll
        for (int e4 = 0; e4 < 8; ++e4) {
            float4 f = *(const float4*)(qptr + e4 * 4);
            qp[e4*2+0] = pack2_bf16(f.x * 0.125f, f.y * 0.125f);
            qp[e4*2+1] = pack2_bf16(f.z * 0.125f, f.w * 0.125f);
        }

        // pow2 dists 64..2048: per-lane row from global (fp32); unroll 1
        // bounds in-flight load regs to one row (32 VGPRs).
        #pragma unroll 1
        for (int dd = 0; dd < NP2; ++dd) {
            const int d = 64 << dd;
            if ((i | 63) >= d) {                // wave-uniform skip
                const int j = max(i - d, 0);
                const float* kr = kb + (size_t)j * E + h * 32;
                float a0 = 0.f, a1 = 0.f, a2 = 0.f, a3 = 0.f;
                #pragma unroll
                for (int e4 = 0; e4 < 8; ++e4) {
                    float4 f = *(const float4*)(kr + e4 * 4);
                    unsigned w0 = qp[e4*2+0], w1 = qp[e4*2+1];
                    a0 = fmaf(f.x, bf_lo(w0), a0); a1 = fmaf(f.y, bf_hi(w0), a1);
                    a2 = fmaf(f.z, bf_lo(w1), a2); a3 = fmaf(f.w, bf_hi(w1), a3);
                }
                scp[dd] += (a0 + a1) + (a2 + a3);
            }
        }

        __builtin_amdgcn_sched_barrier(0);

        // window offsets 0..32 from LDS (bf16); unroll 4 -> 4 b128 in flight
        #pragma unroll 4
        for (int o = 0; o <= WMAX; ++o) {
            const int4* rp = (const int4*)(buf + (tid + (WMAX - o)) * RSTRIDE + h * 64);
            float a0 = 0.f, a1 = 0.f, a2 = 0.f, a3 = 0.f;
            #pragma unroll
            for (int e8 = 0; e8 < 4; ++e8) {
                int4 w = rp[e8];
                unsigned q0 = qp[e8*4+0], q1 = qp[e8*4+1], q2 = qp[e8*4+2], q3 = qp[e8*4+3];
                a0 = fmaf(bf_lo(w.x), bf_lo(q0), a0); a1 = fmaf(bf_hi(w.x), bf_hi(q0), a1);
                a2 = fmaf(bf_lo(w.y), bf_lo(q1), a2); a3 = fmaf(bf_hi(w.y), bf_hi(q1), a3);
                a0 = fmaf(bf_lo(w.z), bf_lo(q2), a0); a1 = fmaf(bf_hi(w.z), bf_hi(q2), a1);
                a2 = fmaf(bf_lo(w.w), bf_lo(q3), a2); a3 = fmaf(bf_hi(w.w), bf_hi(q3), a3);
            }
            scw[o] += (a0 + a1) + (a2 + a3);
        }
        __builtin_amdgcn_sched_barrier(0);
    }

    // ---- masks ----
    #pragma unroll
    for (int o = 0; o <= WMAX; ++o) {
        const bool isp2  = (o > 0) && ((o & (o - 1)) == 0);
        const bool valid = ((o <= win) || isp2) && (o <= i);
        if (!valid) scw[o] = -3.0e38f;
    }
    #pragma unroll
    for (int dd = 0; dd < NP2; ++dd)
        if (i < (64 << dd)) scp[dd] = -3.0e38f;

    // ---- in-lane softmax over 39 candidates; fold 1/den into weights ----
    float m = scw[0];
    #pragma unroll
    for (int o = 1; o <= WMAX; ++o) m = fmaxf(m, scw[o]);
    #pragma unroll
    for (int dd = 0; dd < NP2; ++dd) m = fmaxf(m, scp[dd]);
    float den = 0.f;
    #pragma unroll
    for (int o = 0; o <= WMAX; ++o) { scw[o] = __expf(scw[o] - m); den += scw[o]; }
    #pragma unroll
    for (int dd = 0; dd < NP2; ++dd) { scp[dd] = __expf(scp[dd] - m); den += scp[dd]; }
    const float inv = 1.0f / den;
    #pragma unroll
    for (int o = 0; o <= WMAX; ++o) scw[o] *= inv;
    #pragma unroll
    for (int dd = 0; dd < NP2; ++dd) scp[dd] *= inv;

    __syncthreads();   // done reading K from buf

    // ---- restage V window rows as bf16 ----
    #pragma unroll 6
    for (int it = 0; it < (WROWS * (E / 4)) / QB; ++it) {
        int idx = tid + it * QB;
        int row = idx >> 4, e4 = idx & 15;
        int j = t - WMAX + row; j = max(j, 0);
        const float4 f = *(const float4*)(vb + (size_t)j * E + e4 * 4);
        uint2 pk; pk.x = pack2_bf16(f.x, f.y); pk.y = pack2_bf16(f.z, f.w);
        *(uint2*)(buf + row * RSTRIDE + e4 * 8) = pk;
    }
    __syncthreads();

    // ---- PV: two E-halves; window(LDS, unroll 4) first, pow2(global, unroll 1) last ----
    #pragma unroll 1
    for (int h = 0; h < 2; ++h) {
        float acc[32];
        #pragma unroll
        for (int e = 0; e < 32; ++e) acc[e] = 0.f;

        #pragma unroll 4
        for (int o = 0; o <= WMAX; ++o) {
            const int4* rp = (const int4*)(buf + (tid + (WMAX - o)) * RSTRIDE + h * 64);
            const float po = scw[o];
            #pragma unroll
            for (int e8 = 0; e8 < 4; ++e8) {
                int4 w = rp[e8]; int eb = e8 * 8;
                acc[eb+0] = fmaf(bf_lo(w.x), po, acc[eb+0]);
                acc[eb+1] = fmaf(bf_hi(w.x), po, acc[eb+1]);
                acc[eb+2] = fmaf(bf_lo(w.y), po, acc[eb+2]);
                acc[eb+3] = fmaf(bf_hi(w.y), po, acc[eb+3]);
                acc[eb+4] = fmaf(bf_lo(w.z), po, acc[eb+4]);
                acc[eb+5] = fmaf(bf_hi(w.z), po, acc[eb+5]);
                acc[eb+6] = fmaf(bf_lo(w.w), po, acc[eb+6]);
                acc[eb+7] = fmaf(bf_hi(w.w), po, acc[eb+7]);
            }
        }

        __builtin_amdgcn_sched_barrier(0);

        #pragma unroll 1
        for (int dd = 0; dd < NP2; ++dd) {
            const int d = 64 << dd;
            if ((i | 63) >= d) {
                const int j = max(i - d, 0);
                const float* vr = vb + (size_t)j * E + h * 32;
                const float pd = scp[dd];          // ==0 if masked
                #pragma unroll
                for (int e4 = 0; e4 < 8; ++e4) {
                    float4 f = *(const float4*)(vr + e4 * 4);
                    acc[e4*4+0] = fmaf(f.x, pd, acc[e4*4+0]);
                    acc[e4*4+1] = fmaf(f.y, pd, acc[e4*4+1]);
                    acc[e4*4+2] = fmaf(f.z, pd, acc[e4*4+2]);
                    acc[e4*4+3] = fmaf(f.w, pd, acc[e4*4+3]);
                }
            }
        }

        float* op = out + base + (size_t)i * E + h * 32;
        #pragma unroll
        for (int e4 = 0; e4 < 8; ++e4) {
            float4 o4;
            o4.x = acc[e4*4+0]; o4.y = acc[e4*4+1];
            o4.z = acc[e4*4+2]; o4.w = acc[e4*4+3];
            *(float4*)(op + e4 * 4) = o4;
        }
        __builtin_amdgcn_sched_barrier(0);
    }
}

extern "C" void kernel_launch(void* const* d_in, const int* in_sizes, int n_in,
                              void* d_out, int out_size, void* d_ws, size_t ws_size,
                              hipStream_t stream) {
    const float* q = (const float*)d_in[0];
    const float* k = (const float*)d_in[1];
    const float* v = (const float*)d_in[2];
    const int* win = (const int*)d_in[3];
    float* out = (float*)d_out;

    const int n_rows = in_sizes[0] / E;       // B*H*L = 131072
    const int blocks = n_rows / QB;           // 512
    logsparse_attn<<<blocks, QB, 0, stream>>>(q, k, v, out, win);
}